// Round 2
// baseline (49.130 us; speedup 1.0000x reference)
//
#include <hip/hip_runtime.h>

#define EPS_F 1e-10f

constexpr int N_CLS = 32;
constexpr int B_SZ  = 2048;
constexpr int D_DIM = 1024;

// One block per b (2048 blocks x 256 threads = 4 waves).
// Wave w owns rows n = w*8 .. w*8+7. Fully unrolled row loop, deferred
// wave-level reductions (17 independent butterfly chains at the end) so the
// 32 global_load_dwordx4 per wave stream without DS-chain stalls in between.
__global__ __launch_bounds__(256, 4)
void cosine_sim_kernel(const float* __restrict__ s,
                       const float* __restrict__ target,
                       float* __restrict__ out) {
    const int b    = blockIdx.x;
    const int lane = threadIdx.x & 63;
    const int wave = threadIdx.x >> 6;

    // ---- target row: 4 x float4 per lane ----
    const float4* t4p = reinterpret_cast<const float4*>(target + (size_t)b * D_DIM);
    const float4 t0 = t4p[lane];
    const float4 t1 = t4p[lane + 64];
    const float4 t2 = t4p[lane + 128];
    const float4 t3 = t4p[lane + 192];

    float ss_t;
    {
        float a = fmaf(t0.x, t0.x, fmaf(t0.y, t0.y, fmaf(t0.z, t0.z, t0.w * t0.w)));
        float c = fmaf(t1.x, t1.x, fmaf(t1.y, t1.y, fmaf(t1.z, t1.z, t1.w * t1.w)));
        float d = fmaf(t2.x, t2.x, fmaf(t2.y, t2.y, fmaf(t2.z, t2.z, t2.w * t2.w)));
        float e = fmaf(t3.x, t3.x, fmaf(t3.y, t3.y, fmaf(t3.z, t3.z, t3.w * t3.w)));
        ss_t = (a + c) + (d + e);
    }

    // ---- 8 rows of s, fully unrolled; per-row register accumulators ----
    float dot[8], ssq[8];
    const size_t row_stride4 = (size_t)B_SZ * (D_DIM / 4);  // float4 units
    const float4* base =
        reinterpret_cast<const float4*>(s) +
        ((size_t)(wave * 8) * B_SZ + b) * (size_t)(D_DIM / 4);

#pragma unroll
    for (int k = 0; k < 8; ++k) {
        const float4* p = base + (size_t)k * row_stride4;
        const float4 v0 = p[lane];
        const float4 v1 = p[lane + 64];
        const float4 v2 = p[lane + 128];
        const float4 v3 = p[lane + 192];

        float d = fmaf(t0.x, v0.x, fmaf(t0.y, v0.y, fmaf(t0.z, v0.z, t0.w * v0.w)));
        d = fmaf(t1.x, v1.x, fmaf(t1.y, v1.y, fmaf(t1.z, v1.z, fmaf(t1.w, v1.w, d))));
        d = fmaf(t2.x, v2.x, fmaf(t2.y, v2.y, fmaf(t2.z, v2.z, fmaf(t2.w, v2.w, d))));
        d = fmaf(t3.x, v3.x, fmaf(t3.y, v3.y, fmaf(t3.z, v3.z, fmaf(t3.w, v3.w, d))));

        float q = fmaf(v0.x, v0.x, fmaf(v0.y, v0.y, fmaf(v0.z, v0.z, v0.w * v0.w)));
        q = fmaf(v1.x, v1.x, fmaf(v1.y, v1.y, fmaf(v1.z, v1.z, fmaf(v1.w, v1.w, q))));
        q = fmaf(v2.x, v2.x, fmaf(v2.y, v2.y, fmaf(v2.z, v2.z, fmaf(v2.w, v2.w, q))));
        q = fmaf(v3.x, v3.x, fmaf(v3.y, v3.y, fmaf(v3.z, v3.z, fmaf(v3.w, v3.w, q))));

        dot[k] = d;
        ssq[k] = q;
    }

    // ---- deferred butterfly reductions: 17 independent chains ----
#pragma unroll
    for (int off = 32; off >= 1; off >>= 1) {
        ss_t += __shfl_xor(ss_t, off, 64);
#pragma unroll
        for (int k = 0; k < 8; ++k) {
            dot[k] += __shfl_xor(dot[k], off, 64);
            ssq[k] += __shfl_xor(ssq[k], off, 64);
        }
    }

    if (lane == 0) {
        const float r_t = 1.0f / sqrtf(fmaxf(ss_t, EPS_F));
        float r[8];
#pragma unroll
        for (int k = 0; k < 8; ++k)
            r[k] = dot[k] * r_t * (1.0f / sqrtf(fmaxf(ssq[k], EPS_F)));

        float4* o4 = reinterpret_cast<float4*>(out + (size_t)b * N_CLS + wave * 8);
        o4[0] = make_float4(r[0], r[1], r[2], r[3]);
        o4[1] = make_float4(r[4], r[5], r[6], r[7]);
    }
}

extern "C" void kernel_launch(void* const* d_in, const int* in_sizes, int n_in,
                              void* d_out, int out_size, void* d_ws, size_t ws_size,
                              hipStream_t stream) {
    const float* s      = (const float*)d_in[0];   // [N, B, D] f32
    const float* target = (const float*)d_in[1];   // [B, D] f32
    // d_in[2] = s_label (int64) — unused by the reference output.
    float* out = (float*)d_out;                    // [B, N] f32

    hipLaunchKernelGGL(cosine_sim_kernel, dim3(B_SZ), dim3(256), 0, stream,
                       s, target, out);
}